// Round 4
// baseline (206.472 us; speedup 1.0000x reference)
//
#include <hip/hip_runtime.h>
#include <hip/hip_bf16.h>
#include <math.h>

// KAN 2-layer forward, MI355X (gfx950) — round 4.
//   prep_weights x2 : fold scaler, pad 7->8, bf16            (W1 4MB, W2 4MB)
//   expand_x        : x -> F1 features (8192 x 2048) bf16    (32MB)
//   kan_gemm1       : F1 @ W1^T + exact-GELU -> h f32 (32MB). 128x128, dbuf,
//                     XOR-swizzled LDS, 1 barrier/step.
//   kan_gemm2       : expand(h) in-staging @ W2^T. BM=128, BN=256(full OUT),
//                     split-K=8, dbuf, swizzled LDS, atomicAdd into zeroed out.
// Swizzle: 64B LDS rows (BK=32), phys 16B-slot p = l ^ ((row>>1)&3)
//   -> 8 consecutive rows cover all 32 banks (2 lanes/bank = free).
//   Staged via per-lane swizzled GLOBAL source + linear global_load_lds dest.

typedef __attribute__((ext_vector_type(8))) short bf16x8;   // 8 x bf16 (4 VGPRs)
typedef __attribute__((ext_vector_type(4))) float f32x4;

#define TOKENS 8192
#define D_IN   256
#define D_HID  1024

// ---- exact uniform-cubic-B-spline features (closed form) ----
__device__ __forceinline__ void kan_features(float x, float f[8]) {
    f[0] = x / (1.0f + __expf(-x));          // silu
    const float s = (x + 1.0f) * 1.5f + 3.0f;
    const float cf = floorf(s);
    const float u = s - cf;
    const int c = (int)cf;
    const float u2 = u * u, u3 = u2 * u;
    const float k6 = 1.0f / 6.0f;
    const float v3 = u3 * k6;
    const float v2 = (-3.0f * u3 + 3.0f * u2 + 3.0f * u + 1.0f) * k6;
    const float v1 = (3.0f * u3 - 6.0f * u2 + 4.0f) * k6;
    const float w1 = 1.0f - u;
    const float v0 = w1 * w1 * w1 * k6;
    const bool in = (s >= 0.0f) && (s < 9.0f);
#pragma unroll
    for (int j = 0; j < 6; ++j) {
        int d = c - j;
        float bv = (d == 0) ? v3 : (d == 1) ? v2 : (d == 2) ? v1 : (d == 3) ? v0 : 0.0f;
        f[1 + j] = in ? bv : 0.0f;
    }
    f[7] = 0.0f;
}

__device__ __forceinline__ void features_to_bf16(const float f[8], __hip_bfloat16 fb[8]) {
#pragma unroll
    for (int j = 0; j < 8; ++j) fb[j] = __float2bfloat16(f[j]);
}

// ---------------- weight prep ----------------
__global__ void prep_weights(const float* __restrict__ bw,
                             const float* __restrict__ sw,
                             const float* __restrict__ sc,
                             __hip_bfloat16* __restrict__ Waug, int total) {
    int idx = blockIdx.x * blockDim.x + threadIdx.x;
    if (idx >= total) return;
    float scl = sc[idx];
    __hip_bfloat16 row[8];
    row[0] = __float2bfloat16(bw[idx]);
#pragma unroll
    for (int j = 0; j < 6; ++j)
        row[1 + j] = __float2bfloat16(sw[idx * 6 + j] * scl);
    row[7] = __float2bfloat16(0.0f);
    *(bf16x8*)&Waug[(size_t)idx * 8] = *(bf16x8*)row;
}

// ---------------- x -> F1 features ----------------
__global__ void expand_x(const float* __restrict__ X, __hip_bfloat16* __restrict__ F,
                         int total) {
    int idx = blockIdx.x * blockDim.x + threadIdx.x;
    if (idx >= total) return;
    float f[8];
    kan_features(X[idx], f);
    __hip_bfloat16 fb[8];
    features_to_bf16(f, fb);
    *(bf16x8*)&F[(size_t)idx * 8] = *(bf16x8*)fb;
}

// swizzled LDS element offset (bf16 units) for (row, 16B-slot l)
__device__ __forceinline__ int swz_off(int row, int l) {
    return row * 32 + (l ^ ((row >> 1) & 3)) * 8;
}

// ---------------- GEMM1: H = GELU(F1 @ W1^T), 128x128, dbuf ----------------
__global__ __launch_bounds__(256)
void kan_gemm1(const __hip_bfloat16* __restrict__ A,
               const __hip_bfloat16* __restrict__ W,
               float* __restrict__ H) {
    constexpr int K = D_IN * 8;                 // 2048
    constexpr int BM = 128, BN = 128;
    constexpr int FM = 4, FN = 4;
    __shared__ __hip_bfloat16 Al[2][BM * 32];
    __shared__ __hip_bfloat16 Bl[2][BN * 32];

    const int tid = threadIdx.x;
    const int wid = tid >> 6, lane = tid & 63;
    const int wm = wid >> 1, wn = wid & 1;
    const int lr = lane & 15, lg = lane >> 4;
    const int n0 = blockIdx.x * BM, o0 = blockIdx.y * BN;

    // staging item (same for both halves p=0,1): row = item>>2, slot = item&3
    const int r0 = tid >> 2, s0 = tid & 3;
    const int r1 = (tid + 256) >> 2, s1 = tid & 3;
    const int l0 = s0 ^ ((r0 >> 1) & 3);        // swizzled logical slot for linear dest
    const int l1 = s1 ^ ((r1 >> 1) & 3);

    // fragment read offsets (precomputed, swizzled)
    int aoff[FM], boff[FN];
#pragma unroll
    for (int fm = 0; fm < FM; ++fm) aoff[fm] = swz_off(wm * 64 + fm * 16 + lr, lg);
#pragma unroll
    for (int fn = 0; fn < FN; ++fn) boff[fn] = swz_off(wn * 64 + fn * 16 + lr, lg);

    f32x4 acc[FM][FN] = {};

#define STAGE1(buf, kc)                                                              \
    do {                                                                             \
        __builtin_amdgcn_global_load_lds(                                            \
            (const __attribute__((address_space(1))) void*)(A + (size_t)(n0 + r0) * K + (kc) * 32 + l0 * 8), \
            (__attribute__((address_space(3))) void*)&Al[buf][tid * 8], 16, 0, 0);   \
        __builtin_amdgcn_global_load_lds(                                            \
            (const __attribute__((address_space(1))) void*)(A + (size_t)(n0 + r1) * K + (kc) * 32 + l1 * 8), \
            (__attribute__((address_space(3))) void*)&Al[buf][(tid + 256) * 8], 16, 0, 0); \
        __builtin_amdgcn_global_load_lds(                                            \
            (const __attribute__((address_space(1))) void*)(W + (size_t)(o0 + r0) * K + (kc) * 32 + l0 * 8), \
            (__attribute__((address_space(3))) void*)&Bl[buf][tid * 8], 16, 0, 0);   \
        __builtin_amdgcn_global_load_lds(                                            \
            (const __attribute__((address_space(1))) void*)(W + (size_t)(o0 + r1) * K + (kc) * 32 + l1 * 8), \
            (__attribute__((address_space(3))) void*)&Bl[buf][(tid + 256) * 8], 16, 0, 0); \
    } while (0)

    STAGE1(0, 0);
    __syncthreads();
    for (int kc = 0; kc < K / 32; ++kc) {
        const int cur = kc & 1;
        if (kc + 1 < K / 32) STAGE1(cur ^ 1, kc + 1);
        bf16x8 af[FM], bfr[FN];
#pragma unroll
        for (int fm = 0; fm < FM; ++fm) af[fm] = *(const bf16x8*)&Al[cur][aoff[fm]];
#pragma unroll
        for (int fn = 0; fn < FN; ++fn) bfr[fn] = *(const bf16x8*)&Bl[cur][boff[fn]];
#pragma unroll
        for (int fm = 0; fm < FM; ++fm)
#pragma unroll
            for (int fn = 0; fn < FN; ++fn)
                acc[fm][fn] = __builtin_amdgcn_mfma_f32_16x16x32_bf16(
                    af[fm], bfr[fn], acc[fm][fn], 0, 0, 0);
        __syncthreads();
    }
#undef STAGE1
    // epilogue: exact GELU, f32 store
#pragma unroll
    for (int fm = 0; fm < FM; ++fm) {
#pragma unroll
        for (int fn = 0; fn < FN; ++fn) {
            int col = o0 + wn * 64 + fn * 16 + lr;
#pragma unroll
            for (int r = 0; r < 4; ++r) {
                int row = n0 + wm * 64 + fm * 16 + lg * 4 + r;
                float v = acc[fm][fn][r];
                H[(size_t)row * D_HID + col] = 0.5f * v * (1.0f + erff(v * 0.70710678118f));
            }
        }
    }
}

// ---------------- GEMM2: out += expand(h) @ W2^T, BM=128, BN=256, split-K ----------
__global__ __launch_bounds__(256, 2)
void kan_gemm2(const float* __restrict__ H,
               const __hip_bfloat16* __restrict__ W,
               float* __restrict__ Y) {
    constexpr int BM = 128, BN = 256, OUT = D_IN, KD = D_HID * 8;  // 8192
    constexpr int FM = 4, FN = 8;
    __shared__ __hip_bfloat16 Al[2][BM * 32];
    __shared__ __hip_bfloat16 Bl[2][BN * 32];

    const int tid = threadIdx.x;
    const int wid = tid >> 6, lane = tid & 63;
    const int wm = wid >> 1, wn = wid & 1;
    const int lr = lane & 15, lg = lane >> 4;
    const int n0 = blockIdx.x * BM;

    const int nsteps = KD / 32;                  // 256
    const int per = nsteps / gridDim.z;
    const int ks0 = blockIdx.z * per, ks1 = ks0 + per;

    // A staging: two items (rows r and r+64), h col = tid&3
    const int ar = tid >> 2, ac = tid & 3;
    const float* hp0 = H + (size_t)(n0 + ar) * D_HID + ac;
    const float* hp1 = H + (size_t)(n0 + ar + 64) * D_HID + ac;
    const int aw0 = swz_off(ar, ac);             // swizzled ds_write offsets
    const int aw1 = swz_off(ar + 64, ac);

    // B staging: 4 items, swizzled source
    int brow[4], bslot[4];
#pragma unroll
    for (int p = 0; p < 4; ++p) {
        int item = tid + p * 256;
        brow[p] = item >> 2;
        bslot[p] = (item & 3) ^ ((brow[p] >> 1) & 3);
    }

    int aoff[FM], boff[FN];
#pragma unroll
    for (int fm = 0; fm < FM; ++fm) aoff[fm] = swz_off(wm * 64 + fm * 16 + lr, lg);
#pragma unroll
    for (int fn = 0; fn < FN; ++fn) boff[fn] = swz_off(wn * 128 + fn * 16 + lr, lg);

    f32x4 acc[FM][FN] = {};

#define STAGE2B(buf, kc)                                                             \
    do {                                                                             \
        _Pragma("unroll")                                                            \
        for (int p = 0; p < 4; ++p) {                                                \
            __builtin_amdgcn_global_load_lds(                                        \
                (const __attribute__((address_space(1))) void*)(W + (size_t)brow[p] * KD + (kc) * 32 + bslot[p] * 8), \
                (__attribute__((address_space(3))) void*)&Bl[buf][(tid + p * 256) * 8], 16, 0, 0); \
        }                                                                            \
    } while (0)

#define STAGE2A(buf, h0, h1)                                                         \
    do {                                                                             \
        float f[8]; __hip_bfloat16 fb[8];                                            \
        kan_features(h0, f); features_to_bf16(f, fb);                                \
        *(bf16x8*)&Al[buf][aw0] = *(bf16x8*)fb;                                      \
        kan_features(h1, f); features_to_bf16(f, fb);                                \
        *(bf16x8*)&Al[buf][aw1] = *(bf16x8*)fb;                                      \
    } while (0)

    // prologue: h for ks0 and ks0+1
    float ha0 = hp0[ks0 * 4], ha1 = hp1[ks0 * 4];
    float hb0 = 0.f, hb1 = 0.f;
    if (ks0 + 1 < ks1) { hb0 = hp0[(ks0 + 1) * 4]; hb1 = hp1[(ks0 + 1) * 4]; }
    STAGE2B(0, ks0);
    STAGE2A(0, ha0, ha1);
    __syncthreads();

    for (int kc = ks0; kc < ks1; ++kc) {
        const int cur = (kc - ks0) & 1;
        if (kc + 1 < ks1) {
            STAGE2B(cur ^ 1, kc + 1);
            STAGE2A(cur ^ 1, hb0, hb1);
            if (kc + 2 < ks1) { hb0 = hp0[(kc + 2) * 4]; hb1 = hp1[(kc + 2) * 4]; }
        }
        bf16x8 af[FM], bfr[FN];
#pragma unroll
        for (int fm = 0; fm < FM; ++fm) af[fm] = *(const bf16x8*)&Al[cur][aoff[fm]];
#pragma unroll
        for (int fn = 0; fn < FN; ++fn) bfr[fn] = *(const bf16x8*)&Bl[cur][boff[fn]];
#pragma unroll
        for (int fm = 0; fm < FM; ++fm)
#pragma unroll
            for (int fn = 0; fn < FN; ++fn)
                acc[fm][fn] = __builtin_amdgcn_mfma_f32_16x16x32_bf16(
                    af[fm], bfr[fn], acc[fm][fn], 0, 0, 0);
        __syncthreads();
    }
#undef STAGE2B
#undef STAGE2A

    // epilogue: split-K atomic accumulate
#pragma unroll
    for (int fm = 0; fm < FM; ++fm) {
#pragma unroll
        for (int fn = 0; fn < FN; ++fn) {
            int col = wn * 128 + fn * 16 + lr;
#pragma unroll
            for (int r = 0; r < 4; ++r) {
                int row = n0 + wm * 64 + fm * 16 + lg * 4 + r;
                atomicAdd(&Y[(size_t)row * OUT + col], acc[fm][fn][r]);
            }
        }
    }
}

extern "C" void kernel_launch(void* const* d_in, const int* in_sizes, int n_in,
                              void* d_out, int out_size, void* d_ws, size_t ws_size,
                              hipStream_t stream) {
    const float* x   = (const float*)d_in[0];
    const float* bw1 = (const float*)d_in[1];
    const float* sw1 = (const float*)d_in[2];
    const float* sc1 = (const float*)d_in[3];
    const float* bw2 = (const float*)d_in[4];
    const float* sw2 = (const float*)d_in[5];
    const float* sc2 = (const float*)d_in[6];
    float* out = (float*)d_out;

    char* ws = (char*)d_ws;
    __hip_bfloat16* W1 = (__hip_bfloat16*)ws;                   // 4MB
    __hip_bfloat16* W2 = (__hip_bfloat16*)(ws + (4ull << 20));  // 4MB
    __hip_bfloat16* F1 = (__hip_bfloat16*)(ws + (8ull << 20));  // 32MB
    float*          Hb = (float*)(ws + (40ull << 20));          // 32MB

    if (ws_size < (72ull << 20)) return;

    const int totW = D_HID * D_IN;   // 262144
    prep_weights<<<(totW + 255) / 256, 256, 0, stream>>>(bw1, sw1, sc1, W1, totW);
    prep_weights<<<(totW + 255) / 256, 256, 0, stream>>>(bw2, sw2, sc2, W2, totW);

    hipMemsetAsync(d_out, 0, (size_t)out_size * sizeof(float), stream);

    const int totX = TOKENS * D_IN;  // 2M
    expand_x<<<(totX + 255) / 256, 256, 0, stream>>>(x, F1, totX);

    kan_gemm1<<<dim3(TOKENS / 128, D_HID / 128), 256, 0, stream>>>(F1, W1, Hb);

    kan_gemm2<<<dim3(TOKENS / 128, 1, 8), 256, 0, stream>>>(Hb, W2, out);
}